// Round 21
// baseline (85.108 us; speedup 1.0000x reference)
//
#include <hip/hip_runtime.h>
#include <hip/hip_bf16.h>

typedef __bf16 bf16_t;
typedef __bf16 bf16x8 __attribute__((ext_vector_type(8)));
typedef float f32x4 __attribute__((ext_vector_type(4)));

typedef __attribute__((address_space(3))) void lds_void;
typedef __attribute__((address_space(1))) void gbl_void;

static constexpr int NB  = 4096;  // batch
static constexpr int KIN = 768;   // D_IN
static constexpr int DD  = 256;   // D
static constexpr int FS  = NB * 32;   // F2 k-slice stride (elements)

// ---------------------------------------------------------------------------
// Kernel 1: pack W (KIN x DD, f32) -> Wt2 (bf16, k-slice-major). (R18 form)
// ---------------------------------------------------------------------------
__global__ __launch_bounds__(256) void pack_wt_kernel(
    const float* __restrict__ Wi, const float* __restrict__ Wx,
    bf16_t* __restrict__ Oi, bf16_t* __restrict__ Ox)
{
  __shared__ bf16_t tile[64][66];
  const int b = blockIdx.x;
  const bool isTxt = (b >= 48);
  const int t = isTxt ? b - 48 : b;
  const float* W = isTxt ? Wx : Wi;
  bf16_t* O      = isTxt ? Ox : Oi;
  const int k0 = (t % 12) * 64;     // KIN/64 = 12
  const int c0 = (t / 12) * 64;     // DD/64  = 4
  const int cl = threadIdx.x & 63;
  const int rw = threadIdx.x >> 6;

#pragma unroll
  for (int p = 0; p < 16; ++p) {
    const int kl = p * 4 + rw;
    tile[kl][cl] = (bf16_t)W[(size_t)(k0 + kl) * DD + c0 + cl];
  }
  __syncthreads();
#pragma unroll
  for (int p = 0; p < 16; ++p) {
    const int clo = p * 4 + rw;       // col-within-tile
    const int col = c0 + clo;
    const int k   = k0 + cl;
    O[(size_t)(k >> 5) * 8192 + col * 32 + (k & 31)] = tile[cl][clo];
  }
}

// ---------------------------------------------------------------------------
// Kernel 2: projection GEMM  F = X @ W + b — byte-identical to R19.
// ---------------------------------------------------------------------------
__global__ __launch_bounds__(256) void proj_kernel(
    const float* __restrict__ images, const float* __restrict__ texts,
    const bf16_t* __restrict__ Wti, const bf16_t* __restrict__ Wtt,
    const float* __restrict__ b_img, const float* __restrict__ b_txt,
    const float* __restrict__ cs_w,
    bf16_t* __restrict__ Fi, bf16_t* __restrict__ Ft,
    float* __restrict__ rni, float* __restrict__ si,
    float* __restrict__ rnt, float* __restrict__ st)
{
  __shared__ float xs[16 * KIN];    // 48 KB staged X tile (swizzled 16B units)
  __shared__ float lnsq[4][16];
  __shared__ float lsdt[4][16];

  const int bid = blockIdx.x;
  const bool isTxt = (bid >= 256);
  const float* X    = isTxt ? texts : images;
  const bf16_t* Wt  = isTxt ? Wtt : Wti;
  const float* bias = isTxt ? b_txt : b_img;
  const float* csw  = cs_w + (isTxt ? DD : 0);
  bf16_t* F     = isTxt ? Ft : Fi;
  float* rnorm  = isTxt ? rnt : rni;
  float* svec   = isTxt ? st : si;

  const int tid  = threadIdx.x;
  const int lane = tid & 63;
  const int wave = tid >> 6;
  const int lrow = lane & 15;
  const int g    = lane >> 4;
  const int rb   = (bid & 255) * 16;
  const int cwb  = wave * 64;

#pragma unroll
  for (int i = 0; i < 12; ++i) {
    const int U   = wave * 768 + i * 64 + lane;
    const int row = U / 192;
    const int su  = U - row * 192;
    const int ou  = su ^ (row & 7);
    const float* gp = X + (size_t)(rb + row) * KIN + ou * 4;
    char* lb = (char*)xs + wave * 12288 + i * 1024;   // wave-uniform base
    __builtin_amdgcn_global_load_lds((const gbl_void*)gp, (lds_void*)lb, 16, 0, 0);
  }
  __syncthreads();

  const f32x4 fzero = {0.f, 0.f, 0.f, 0.f};
  f32x4 acc[4];
#pragma unroll
  for (int n = 0; n < 4; ++n) acc[n] = fzero;

  const bf16_t* wtb  = Wt + (size_t)(cwb + lrow) * 32 + g * 8;
  const float*  xrow = xs + lrow * KIN;
  const int     rsw  = lrow & 7;

#pragma unroll 4
  for (int ks = 0; ks < KIN / 32; ++ks) {
    const int u0 = ks * 8 + g * 2;
    f32x4 x0 = *reinterpret_cast<const f32x4*>(xrow + ((u0    ) ^ rsw) * 4);
    f32x4 x1 = *reinterpret_cast<const f32x4*>(xrow + ((u0 + 1) ^ rsw) * 4);
    bf16x8 a;
#pragma unroll
    for (int e = 0; e < 4; ++e) { a[e] = (bf16_t)x0[e]; a[e + 4] = (bf16_t)x1[e]; }
#pragma unroll
    for (int n = 0; n < 4; ++n) {
      bf16x8 bfr = *reinterpret_cast<const bf16x8*>(wtb + ks * 8192 + n * 512);
      acc[n] = __builtin_amdgcn_mfma_f32_16x16x32_bf16(a, bfr, acc[n], 0, 0, 0);
    }
  }

  float nsq[4] = {0.f, 0.f, 0.f, 0.f};
  float sdt[4] = {0.f, 0.f, 0.f, 0.f};
#pragma unroll
  for (int n = 0; n < 4; ++n) {
    const int col = cwb + n * 16 + lrow;
    const float bn = bias[col];
    const float wn = csw[col];
    const size_t cbase = (size_t)(col >> 5) * FS + (col & 31);
#pragma unroll
    for (int r = 0; r < 4; ++r) {
      float v = acc[n][r] + bn;
      const int row = rb + g * 4 + r;
      F[cbase + row * 32] = (bf16_t)v;    // k-slice-major store
      nsq[r] += v * v;
      sdt[r] += v * wn;
    }
  }
#pragma unroll
  for (int msk = 8; msk >= 1; msk >>= 1) {
#pragma unroll
    for (int r = 0; r < 4; ++r) {
      nsq[r] += __shfl_xor(nsq[r], msk, 64);
      sdt[r] += __shfl_xor(sdt[r], msk, 64);
    }
  }
  if (lrow == 0) {
#pragma unroll
    for (int r = 0; r < 4; ++r) {
      lnsq[wave][g * 4 + r] = nsq[r];
      lsdt[wave][g * 4 + r] = sdt[r];
    }
  }
  __syncthreads();
  if (tid < 16) {
    float tn = 0.f, ts = 0.f;
#pragma unroll
    for (int w2 = 0; w2 < 4; ++w2) { tn += lnsq[w2][tid]; ts += lsdt[w2][tid]; }
    rnorm[rb + tid] = 1.0f / sqrtf(tn);
    svec [rb + tid] = ts;
  }
}

// ---------------------------------------------------------------------------
// Kernel 3: sim = Fi @ Ft^T + fused epilogue.
// R21 change (sim only): 32 KB LDS bounce processed in TWO 64-row halves
// with the wave->row remap (each wave's 4 row-fragments span both halves:
// rows wr*32+{0,16} and 64+wr*32+{0,16}) -> 4 blocks/CU (16 waves/CU),
// letting one block's GEMM overlap another's streaming. Plain stores (R9
// finding), NT edge loads in the epilogue, K-loop still k-slice-major
// coalesced. __launch_bounds__(256,4) caps VGPR at 128.
// ---------------------------------------------------------------------------
__global__ __launch_bounds__(256, 4) void sim_kernel(
    const bf16_t* __restrict__ Fi, const bf16_t* __restrict__ Ft,
    const float* __restrict__ rni, const float* __restrict__ si,
    const float* __restrict__ rnt, const float* __restrict__ st,
    const float* __restrict__ cs_b, const float* __restrict__ edge,
    float* __restrict__ out_final, float* __restrict__ out_sim,
    float* __restrict__ out_causal)
{
  __shared__ float smem[64 * 128];   // 32 KB, XOR-swizzled

  const int bid = blockIdx.x;
  const int swz = (bid & 7) * 128 + (bid >> 3);
  const int bx = swz & 31;   // col tile
  const int by = swz >> 5;   // row tile

  const int tid  = threadIdx.x;
  const int lane = tid & 63;
  const int wave = tid >> 6;
  const int wr = wave >> 1;
  const int wc = wave & 1;
  const int lrow = lane & 15;
  const int g    = lane >> 4;

  const int rowG0 = by * 128;
  const int colG0 = bx * 128;
  const int colBase = colG0 + wc * 64;

  const f32x4 fzero = {0.f, 0.f, 0.f, 0.f};
  f32x4 acc[4][4];   // m = h*2+m2: rows rowG0 + h*64 + wr*32 + m2*16
#pragma unroll
  for (int m = 0; m < 4; ++m)
#pragma unroll
    for (int n = 0; n < 4; ++n) acc[m][n] = fzero;

  // k-slice-major per-lane bases (contiguous 1 KB per wave load)
  const size_t arowL = (size_t)(rowG0 + wr * 32 + lrow) * 32 + g * 8;
  const size_t brow  = (size_t)(colBase + lrow) * 32 + g * 8;

#pragma unroll 2
  for (int ks = 0; ks < DD / 32; ++ks) {
    const size_t so = (size_t)ks * FS;
    bf16x8 a[4], b[4];
#pragma unroll
    for (int m = 0; m < 4; ++m) {
      const int h = m >> 1, m2 = m & 1;
      a[m] = *reinterpret_cast<const bf16x8*>(Fi + so + arowL + h * 2048 + m2 * 512);
    }
#pragma unroll
    for (int n = 0; n < 4; ++n)
      b[n] = *reinterpret_cast<const bf16x8*>(Ft + so + brow + n * 512);
#pragma unroll
    for (int m = 0; m < 4; ++m)
#pragma unroll
      for (int n = 0; n < 4; ++n)
        acc[m][n] = __builtin_amdgcn_mfma_f32_16x16x32_bf16(a[m], b[n], acc[m][n], 0, 0, 0);
  }

  const float cb = cs_b[0];
  float rntv[4];
#pragma unroll
  for (int n = 0; n < 4; ++n) rntv[n] = rnt[colBase + n * 16 + lrow];

#pragma unroll
  for (int h = 0; h < 2; ++h) {
    // ---- fragment write: all 4 waves write their 32 rows of this half ----
#pragma unroll
    for (int m2 = 0; m2 < 2; ++m2) {
      const int m = h * 2 + m2;
      const int rbase = wr * 32 + m2 * 16 + g * 4;   // local row base (0..63)
      float rn[4];
#pragma unroll
      for (int r = 0; r < 4; ++r) rn[r] = rni[rowG0 + h * 64 + rbase + r];
#pragma unroll
      for (int n = 0; n < 4; ++n) {
        const int cl = wc * 64 + n * 16 + lrow;
#pragma unroll
        for (int r = 0; r < 4; ++r) {
          const int rl = rbase + r;
          smem[rl * 128 + (cl ^ ((rl & 7) << 2))] = acc[m][n][r] * rn[r] * rntv[n];
        }
      }
    }
    __syncthreads();

    // ---- streaming epilogue for this half: 8192 elems = 256 thr x 8 x f32x4
#pragma unroll
    for (int it = 0; it < 8; ++it) {
      const int e  = (it * 256 + tid) * 4;
      const int r0 = e >> 7;        // 0..63
      const int c  = e & 127;       // multiple of 4
      const int grow = rowG0 + h * 64 + r0;
      const size_t idx = (size_t)grow * NB + colG0 + c;
      const f32x4 ew4 = __builtin_nontemporal_load(
          reinterpret_cast<const f32x4*>(edge + idx));
      const f32x4 sv4 = *reinterpret_cast<const f32x4*>(&smem[r0 * 128 + (c ^ ((r0 & 7) << 2))]);
      const float sir = si[grow];
      const f32x4 st4 = *reinterpret_cast<const f32x4*>(st + colG0 + c);
      f32x4 ca4, fin4;
#pragma unroll
      for (int j = 0; j < 4; ++j) {
        const float strength = sir + st4[j] + cb;
        ca4[j]  = ew4[j] * strength;
        fin4[j] = sv4[j] + 0.3f * ca4[j];
      }
      *reinterpret_cast<f32x4*>(out_sim    + idx) = sv4;
      *reinterpret_cast<f32x4*>(out_causal + idx) = ca4;
      *reinterpret_cast<f32x4*>(out_final  + idx) = fin4;
    }
    if (h == 0) __syncthreads();   // LDS reuse: drain reads before half-1 writes
  }
}

// ---------------------------------------------------------------------------
extern "C" void kernel_launch(void* const* d_in, const int* in_sizes, int n_in,
                              void* d_out, int out_size, void* d_ws, size_t ws_size,
                              hipStream_t stream) {
  const float* images = (const float*)d_in[0];
  const float* texts  = (const float*)d_in[1];
  const float* W_img  = (const float*)d_in[2];
  const float* b_img  = (const float*)d_in[3];
  const float* W_txt  = (const float*)d_in[4];
  const float* b_txt  = (const float*)d_in[5];
  const float* cs_w   = (const float*)d_in[6];
  const float* cs_b   = (const float*)d_in[7];
  const float* edge   = (const float*)d_in[8];

  float* out_final  = (float*)d_out;
  float* out_sim    = out_final + (size_t)NB * NB;
  float* out_causal = out_sim   + (size_t)NB * NB;

  // Workspace layout (~4.9 MiB total)
  char* ws = (char*)d_ws;
  bf16_t* Fi  = (bf16_t*)ws;                     // 4096*256 bf16 (k-slice-major)
  bf16_t* Ft  = Fi  + (size_t)NB * DD;           // 4096*256 bf16 (k-slice-major)
  bf16_t* Wti = Ft  + (size_t)NB * DD;           // 256*768 bf16 (k-slice-major)
  bf16_t* Wtt = Wti + (size_t)DD * KIN;          // 256*768 bf16 (k-slice-major)
  float*  rni = (float*)(Wtt + (size_t)DD * KIN);
  float*  siv = rni + NB;
  float*  rnt = siv + NB;
  float*  stv = rnt + NB;

  pack_wt_kernel<<<96, 256, 0, stream>>>(W_img, W_txt, Wti, Wtt);
  proj_kernel<<<512, 256, 0, stream>>>(images, texts, Wti, Wtt, b_img, b_txt, cs_w,
                                       Fi, Ft, rni, siv, rnt, stv);
  sim_kernel<<<1024, 256, 0, stream>>>(Fi, Ft, rni, siv, rnt, stv, cs_b, edge,
                                       out_final, out_sim, out_causal);
}